// Round 3
// baseline (404.987 us; speedup 1.0000x reference)
//
#include <hip/hip_runtime.h>
#include <stdint.h>

#define E_EDGES 131072
#define NELEC 1024
#define NNUC 256
#define NBLK 16          // hist/scatter blocks per type

typedef __attribute__((ext_vector_type(8))) short short8;
typedef __attribute__((ext_vector_type(4))) float float4_t;
typedef __attribute__((ext_vector_type(4))) int int4_t;

__device__ inline float silu_f(float x){ return x / (1.0f + expf(-x)); }

__device__ inline short f2bf_rne(float x){
    union { float f; uint32_t u; } a; a.f = x;
    return (short)((a.u + 0x7fffu + ((a.u >> 16) & 1u)) >> 16);
}
__device__ inline float bf2f(short h){
    union { uint32_t u; float f; } a; a.u = ((uint32_t)(uint16_t)h) << 16;
    return a.f;
}

// split 8 floats into hi/lo bf16 fragments (truncation split; lo captures residual)
__device__ inline void cvt_split8(float4_t x0, float4_t x1, short8& hi, short8& lo){
    union U8 { short8 s; uint32_t u[4]; } H, L;
    float f[8] = {x0[0],x0[1],x0[2],x0[3],x1[0],x1[1],x1[2],x1[3]};
    #pragma unroll
    for (int k = 0; k < 4; k++){
        union { float f; uint32_t u; } a, b, am, bm, la, lb;
        a.f = f[2*k]; b.f = f[2*k+1];
        am.u = a.u & 0xFFFF0000u; bm.u = b.u & 0xFFFF0000u;
        // dword = [hi16(f2k+1) : hi16(f2k)], low short = f2k
        H.u[k] = __builtin_amdgcn_perm(b.u, a.u, 0x07060302u);
        la.f = a.f - am.f; lb.f = b.f - bm.f;
        L.u[k] = __builtin_amdgcn_perm(lb.u, la.u, 0x07060302u);
    }
    hi = H.s; lo = L.s;
}

// ================= prep: h-table + W_w swizzle + out-init + histogram ========
__global__ __launch_bounds__(256) void prep_kernel(
    const float* __restrict__ s_elec, const float* __restrict__ v_elec,
    const float* __restrict__ s_nuc,
    const float* __restrict__ W_h1, const float* __restrict__ W_h2,
    const float* __restrict__ W_w,
    const int* __restrict__ receivers,
    float* __restrict__ h_out, short* __restrict__ fragH, short* __restrict__ fragL,
    int* __restrict__ bh, float* __restrict__ out)
{
    int b = blockIdx.x, tid = threadIdx.x;
    __shared__ float sls[8][64];
    __shared__ float hidls[128][8];
    __shared__ int hist[1024];

    if (b < 288){
        int t, node0;
        if (b < 32){ t = 0; node0 = b*8; }
        else if (b < 160){ t = 1; node0 = (b-32)*8; }
        else { t = 2; node0 = (b-160)*8; }
        int tp = t + 1;
        const float* src = (t == 0) ? s_nuc : s_elec;
        long hbase = (t == 0) ? 0 : (t == 1 ? (long)NNUC*192 : (long)NNUC*192 + (long)NELEC*192);
        for (int i = tid; i < 512; i += 256){ int n = i >> 6, f = i & 63; sls[n][f] = src[(node0+n)*64 + f]; }
        __syncthreads();
        {
            int j = tid & 127, nh = tid >> 7;
            const float* w1 = W_h1 + (long)tp*64*128;
            float a0=0,a1=0,a2=0,a3=0;
            #pragma unroll 8
            for (int f = 0; f < 64; f++){
                float w = w1[f*128 + j];
                a0 += sls[nh*4+0][f]*w; a1 += sls[nh*4+1][f]*w;
                a2 += sls[nh*4+2][f]*w; a3 += sls[nh*4+3][f]*w;
            }
            float4_t hv = { silu_f(a0), silu_f(a1), silu_f(a2), silu_f(a3) };
            *(float4_t*)&hidls[j][nh*4] = hv;
        }
        __syncthreads();
        if (tid < 192){
            const float* w2 = W_h2 + (long)tp*128*192;
            float acc[8] = {0,0,0,0,0,0,0,0};
            #pragma unroll 4
            for (int h = 0; h < 128; h++){
                float w = w2[h*192 + tid];
                float4_t ha = *(float4_t*)&hidls[h][0];
                float4_t hb = *(float4_t*)&hidls[h][4];
                acc[0]+=ha[0]*w; acc[1]+=ha[1]*w; acc[2]+=ha[2]*w; acc[3]+=ha[3]*w;
                acc[4]+=hb[0]*w; acc[5]+=hb[1]*w; acc[6]+=hb[2]*w; acc[7]+=hb[3]*w;
            }
            #pragma unroll
            for (int n = 0; n < 8; n++) h_out[hbase + (long)(node0+n)*192 + tid] = acc[n];
        }
    } else if (b < 291){
        int t = b - 288, tp = t + 1;
        const float* W = W_w + (long)tp*64*192;
        for (int idx = tid; idx < 12288; idx += 256){
            int j    = idx & 7;
            int lane = (idx >> 3) & 63;
            int ks   = (idx >> 9) & 1;
            int nt   = idx >> 10;
            int k = ks*32 + ((lane >> 4) & 3)*8 + j;
            int n = nt*16 + (lane & 15);
            float v = W[k*192 + n];
            short hi = f2bf_rne(v);
            short lo = f2bf_rne(v - bf2f(hi));
            fragH[t*12288 + idx] = hi;
            fragL[t*12288 + idx] = lo;
        }
    } else if (b < 547){
        int i = (b - 291)*256 + tid;
        int n = i >> 6, c4 = i & 63;
        float4_t v;
        if (c4 < 16) v = *(const float4_t*)(s_elec + n*64 + c4*4);
        else         v = *(const float4_t*)(v_elec + n*192 + (c4-16)*4);
        *(float4_t*)(out + n*256 + c4*4) = v;
    } else {
        int hb = b - 547, t = hb >> 4, blk = hb & 15;
        for (int i = tid; i < 1024; i += 256) hist[i] = 0;
        __syncthreads();
        long base = (long)(t+1)*E_EDGES + blk*8192;
        #pragma unroll 4
        for (int it = 0; it < 32; it++){
            int r = receivers[base + it*256 + tid];
            atomicAdd(&hist[r], 1);
        }
        __syncthreads();
        for (int bin = tid; bin < 1024; bin += 256)
            bh[(t*1024 + bin)*NBLK + blk] = hist[bin];
    }
}

// ================= scan ======================================================
__global__ __launch_bounds__(1024) void scan_kernel(int* __restrict__ bh,
                                                    int* __restrict__ offs,
                                                    int* __restrict__ counts){
    __shared__ int buf[1024];
    int tid = threadIdx.x;
    int base = tid*48;
    int vals[48];
    const int4_t* p = (const int4_t*)(bh + base);
    int s = 0;
    #pragma unroll
    for (int j = 0; j < 12; j++){
        int4_t x = p[j];
        vals[j*4+0]=x[0]; vals[j*4+1]=x[1]; vals[j*4+2]=x[2]; vals[j*4+3]=x[3];
        s += x[0]+x[1]+x[2]+x[3];
    }
    buf[tid] = s;
    __syncthreads();
    int x = s;
    for (int off = 1; off < 1024; off <<= 1){
        int y = (tid >= off) ? buf[tid - off] : 0;
        __syncthreads();
        x += y; buf[tid] = x;
        __syncthreads();
    }
    int run = x - s;
    #pragma unroll
    for (int k = 0; k < 3; k++){
        int tb = tid*3 + k;
        offs[tb] = run;
        int c = 0;
        #pragma unroll
        for (int j = 0; j < 16; j++){
            int v = vals[k*16 + j];
            bh[base + k*16 + j] = run;
            run += v; c += v;
        }
        counts[tb] = c;
    }
}

// ================= scatter ===================================================
__global__ __launch_bounds__(256) void scatter_kernel(const int* __restrict__ receivers,
                                                      const int* __restrict__ senders,
                                                      const int* __restrict__ bh,
                                                      int* __restrict__ sorted){
    int hb = blockIdx.x, t = hb >> 4, blk = hb & 15;
    int tid = threadIdx.x;
    __shared__ int cur[1024];
    for (int bin = tid; bin < 1024; bin += 256) cur[bin] = bh[(t*1024 + bin)*NBLK + blk];
    __syncthreads();
    long base = (long)(t+1)*E_EDGES + blk*8192;
    #pragma unroll 2
    for (int it = 0; it < 32; it++){
        int e = blk*8192 + it*256 + tid;
        int r = receivers[base + it*256 + tid];
        int snd = senders[base + it*256 + tid];
        int pos = atomicAdd(&cur[r], 1);
        sorted[pos] = e | (snd << 17);
    }
}

// ================= main: barrier-free per-wave edge loop =====================
// Each wave owns 16 features (3 B-tiles); loads its own A fragments directly
// from dist (no LDS staging, no per-group __syncthreads).
__global__ __launch_bounds__(256, 3) void main_kernel(
    const float* __restrict__ dist, const float* __restrict__ dirs,
    const float* __restrict__ v_elec, const float* __restrict__ v_nuc,
    const float* __restrict__ W_V, const float* __restrict__ W_U,
    const float* __restrict__ W_g1, const float* __restrict__ W_g2,
    const float* __restrict__ h_tab, const short* __restrict__ fragH, const short* __restrict__ fragL,
    const int* __restrict__ counts, const int* __restrict__ offs, const int* __restrict__ sorted,
    float* __restrict__ out)
{
    int b = blockIdx.x;
    int t = b >> 10, node = b & 1023, tp = t + 1;
    const float* v_src = (t == 0) ? v_nuc : v_elec;
    long hbase = (t == 0) ? 0 : (t == 1 ? (long)NNUC*192 : (long)NNUC*192 + (long)NELEC*192);
    const float* hsrc = h_tab + hbase;
    const float* dbase = dist + (long)tp*E_EDGES*64;
    const float* dirbase = dirs + (long)tp*E_EDGES*3;

    int tid = threadIdx.x;
    int w = tid >> 6, l = tid & 63;
    int q = l >> 4, c16 = l & 15;
    int d = w*16 + c16;

    __shared__ float zs[64];
    __shared__ float zv[64][3];
    __shared__ float VvL[192], UvL[192];
    __shared__ float gin[128], hidl[128], aL[192], vdotL[64];

    // B fragments (W_w hi/lo) in registers: wave w -> col tiles {w, w+4, w+8}
    short8 bhf[3][2], blf[3][2];
    #pragma unroll
    for (int ni = 0; ni < 3; ni++){
        int nt = w + ni*4;
        #pragma unroll
        for (int ks = 0; ks < 2; ks++){
            long base = (long)t*12288 + ((nt*2 + ks)*64 + l)*8;
            bhf[ni][ks] = *(const short8*)(fragH + base);
            blf[ni][ks] = *(const short8*)(fragL + base);
        }
    }

    float acc_s = 0.f, acc_v0 = 0.f, acc_v1 = 0.f, acc_v2 = 0.f;

    int deg   = counts[t*1024 + node];
    int start = offs[t*1024 + node];
    int ngroups = (deg + 15) >> 4;

    const float4_t z4 = {0.f,0.f,0.f,0.f};
    int seC = 0;
    float4_t A0 = z4, A1 = z4, A2 = z4, A3 = z4;

    if (ngroups > 0){
        int rel = c16;
        int idx = start + (rel < deg ? rel : deg - 1);
        seC = sorted[idx];
        const float* rp = dbase + (long)(seC & 131071)*64 + q*8;
        A0 = *(const float4_t*)(rp);
        A1 = *(const float4_t*)(rp + 4);
        A2 = *(const float4_t*)(rp + 32);
        A3 = *(const float4_t*)(rp + 36);
        if (rel >= deg){ A0 = z4; A1 = z4; A2 = z4; A3 = z4; }
    }

    for (int g = 0; g < ngroups; g++){
        // ---- prefetch next group's A (in flight across this group's compute)
        int seN = 0;
        float4_t N0 = z4, N1 = z4, N2 = z4, N3 = z4;
        if (g + 1 < ngroups){
            int rel = (g+1)*16 + c16;
            int idx = start + (rel < deg ? rel : deg - 1);
            seN = sorted[idx];
            const float* rp = dbase + (long)(seN & 131071)*64 + q*8;
            N0 = *(const float4_t*)(rp);
            N1 = *(const float4_t*)(rp + 4);
            N2 = *(const float4_t*)(rp + 32);
            N3 = *(const float4_t*)(rp + 36);
            if (rel >= deg){ N0 = z4; N1 = z4; N2 = z4; N3 = z4; }
        }

        // ---- current group's dirs (this lane's row r16) ----
        const float* dp = dirbase + (long)(seC & 131071)*3;
        float dr0 = dp[0], dr1 = dp[1], dr2 = dp[2];

        // ---- gathers (independent of MFMA; issue early) ----
        float hg[4][3], vg[4][3];
        #pragma unroll
        for (int reg = 0; reg < 4; reg++){
            int sse = __shfl(seC, q*4 + reg, 64);
            int s = ((unsigned)sse) >> 17;
            const float* hp = hsrc + (long)s*192 + d;
            hg[reg][0] = hp[0]; hg[reg][1] = hp[64]; hg[reg][2] = hp[128];
            const float* vp = v_src + (long)s*192 + d*3;
            vg[reg][0] = vp[0]; vg[reg][1] = vp[1]; vg[reg][2] = vp[2];
        }

        // ---- convert + MFMA (split-bf16 3-term) ----
        short8 ah0, al0, ah1, al1;
        cvt_split8(A0, A1, ah0, al0);
        cvt_split8(A2, A3, ah1, al1);
        float4_t C[3];
        #pragma unroll
        for (int ni = 0; ni < 3; ni++){
            float4_t acc = z4;
            acc = __builtin_amdgcn_mfma_f32_16x16x32_bf16(ah0, bhf[ni][0], acc, 0, 0, 0);
            acc = __builtin_amdgcn_mfma_f32_16x16x32_bf16(ah1, bhf[ni][1], acc, 0, 0, 0);
            acc = __builtin_amdgcn_mfma_f32_16x16x32_bf16(ah0, blf[ni][0], acc, 0, 0, 0);
            acc = __builtin_amdgcn_mfma_f32_16x16x32_bf16(ah1, blf[ni][1], acc, 0, 0, 0);
            acc = __builtin_amdgcn_mfma_f32_16x16x32_bf16(al0, bhf[ni][0], acc, 0, 0, 0);
            acc = __builtin_amdgcn_mfma_f32_16x16x32_bf16(al1, bhf[ni][1], acc, 0, 0, 0);
            C[ni] = acc;
        }

        // ---- epilogue: phi = we*hx; accumulate z_s, z_v ----
        #pragma unroll
        for (int reg = 0; reg < 4; reg++){
            int src = q*4 + reg;
            float e0 = __shfl(dr0, src, 64);
            float e1 = __shfl(dr1, src, 64);
            float e2 = __shfl(dr2, src, 64);
            acc_s += C[0][reg] * hg[reg][0];
            float pvv = C[1][reg] * hg[reg][1];
            acc_v0 += pvv * vg[reg][0];
            acc_v1 += pvv * vg[reg][1];
            acc_v2 += pvv * vg[reg][2];
            float pvs = C[2][reg] * hg[reg][2];
            acc_v0 += pvs * e0;
            acc_v1 += pvs * e1;
            acc_v2 += pvs * e2;
        }

        seC = seN; A0 = N0; A1 = N1; A2 = N2; A3 = N3;
    }

    // ---- cross-quad reduction (C rows live in different quads) ----
    acc_s  += __shfl_xor(acc_s, 16);  acc_s  += __shfl_xor(acc_s, 32);
    acc_v0 += __shfl_xor(acc_v0, 16); acc_v0 += __shfl_xor(acc_v0, 32);
    acc_v1 += __shfl_xor(acc_v1, 16); acc_v1 += __shfl_xor(acc_v1, 32);
    acc_v2 += __shfl_xor(acc_v2, 16); acc_v2 += __shfl_xor(acc_v2, 32);
    if (l < 16){
        zs[d] = acc_s;
        zv[d][0] = acc_v0; zv[d][1] = acc_v1; zv[d][2] = acc_v2;
    }
    __syncthreads();

    // ---- node update ----
    if (tid < 192){
        int i = tid >> 6, f = tid & 63;
        const float* wv = W_V + (long)tp*64*64;
        const float* wu = W_U + (long)tp*64*64;
        float av = 0.f, au = 0.f;
        #pragma unroll 8
        for (int dd = 0; dd < 64; dd++){
            float z = zv[dd][i];
            av += z * wv[dd*64 + f];
            au += z * wu[dd*64 + f];
        }
        VvL[f*3 + i] = av;
        UvL[f*3 + i] = au;
    }
    __syncthreads();
    if (tid < 64){
        int f = tid;
        float v0 = VvL[f*3], v1 = VvL[f*3+1], v2 = VvL[f*3+2];
        float u0 = UvL[f*3], u1 = UvL[f*3+1], u2 = UvL[f*3+2];
        gin[f] = zs[f];
        gin[64 + f] = v0*v0 + v1*v1 + v2*v2;
        vdotL[f] = u0*v0 + u1*v1 + u2*v2;
    }
    __syncthreads();
    if (tid < 128){
        const float* w1 = W_g1 + (long)tp*128*128;
        float acc = 0.f;
        #pragma unroll 8
        for (int c = 0; c < 128; c++) acc += gin[c] * w1[c*128 + tid];
        hidl[tid] = silu_f(acc);
    }
    __syncthreads();
    if (tid < 192){
        const float* w2 = W_g2 + (long)tp*128*192;
        float acc = 0.f;
        #pragma unroll 8
        for (int h = 0; h < 128; h++) acc += hidl[h] * w2[h*192 + tid];
        aL[tid] = acc;
    }
    __syncthreads();
    if (tid < 64){
        int f = tid;
        float upd = aL[128 + f] * vdotL[f] + aL[f];
        atomicAdd(&out[node*256 + f], upd);
    }
    if (tid < 192){
        int i = tid >> 6, f = tid & 63;
        float updv = UvL[f*3 + i] * aL[64 + f];
        atomicAdd(&out[node*256 + 64 + f*3 + i], updv);
    }
}

// ================= launcher ==================================================
extern "C" void kernel_launch(void* const* d_in, const int* in_sizes, int n_in,
                              void* d_out, int out_size, void* d_ws, size_t ws_size,
                              hipStream_t stream){
    const float* s_elec  = (const float*)d_in[0];
    const float* v_elec  = (const float*)d_in[1];
    const float* s_nuc   = (const float*)d_in[2];
    const float* v_nuc   = (const float*)d_in[3];
    const float* dist    = (const float*)d_in[4];
    const float* dirs    = (const float*)d_in[5];
    const float* W_w     = (const float*)d_in[6];
    const float* W_h1    = (const float*)d_in[7];
    const float* W_h2    = (const float*)d_in[8];
    const float* W_g1    = (const float*)d_in[9];
    const float* W_g2    = (const float*)d_in[10];
    const float* W_V     = (const float*)d_in[11];
    const float* W_U     = (const float*)d_in[12];
    const int* senders   = (const int*)d_in[13];
    const int* receivers = (const int*)d_in[14];
    float* out = (float*)d_out;
    char* ws = (char*)d_ws;

    float* h_tab  = (float*)(ws + 0);          // 1769472 B
    short* fragH  = (short*)(ws + 1769472);    // 73728 B
    short* fragL  = (short*)(ws + 1843200);    // 73728 B
    int*   bh     = (int*)  (ws + 1916928);    // 196608 B
    int*   offs   = (int*)  (ws + 2113536);    // 12288 B
    int*   counts = (int*)  (ws + 2125824);    // 12288 B
    int*   sorted = (int*)  (ws + 2138112);    // 1572864 B -> end 3710976
    if (ws_size < 3710976) return;

    prep_kernel<<<dim3(595), dim3(256), 0, stream>>>(
        s_elec, v_elec, s_nuc, W_h1, W_h2, W_w, receivers,
        h_tab, fragH, fragL, bh, out);
    scan_kernel<<<dim3(1), dim3(1024), 0, stream>>>(bh, offs, counts);
    scatter_kernel<<<dim3(48), dim3(256), 0, stream>>>(receivers, senders, bh, sorted);
    main_kernel<<<dim3(3072), dim3(256), 0, stream>>>(
        dist, dirs, v_elec, v_nuc, W_V, W_U, W_g1, W_g2,
        h_tab, fragH, fragL, counts, offs, sorted, out);
}

// Round 4
// 363.287 us; speedup vs baseline: 1.1148x; 1.1148x over previous
//
#include <hip/hip_runtime.h>
#include <stdint.h>

#define E_EDGES 131072
#define NELEC 1024
#define NNUC 256
#define MAXCHUNK 256
#define NBLK 16          // hist/scatter blocks per type

typedef unsigned short ushort_t;
typedef __attribute__((ext_vector_type(8))) short short8;
typedef __attribute__((ext_vector_type(4))) short short4_t;
typedef __attribute__((ext_vector_type(4))) float float4_t;
typedef __attribute__((ext_vector_type(4))) int int4_t;
typedef __attribute__((ext_vector_type(2))) unsigned int uint2_t;

__device__ inline float silu_f(float x){ return x / (1.0f + expf(-x)); }

__device__ inline short f2bf_rne(float x){
    union { float f; uint32_t u; } a; a.f = x;
    return (short)((a.u + 0x7fffu + ((a.u >> 16) & 1u)) >> 16);
}
__device__ inline float bf2f(short h){
    union { uint32_t u; float f; } a; a.u = ((uint32_t)(uint16_t)h) << 16;
    return a.f;
}
__device__ inline ushort_t bfu(float x){ return (ushort_t)f2bf_rne(x); }
__device__ inline float asf_lo(uint32_t u){ union { uint32_t u; float f; } a; a.u = u << 16; return a.f; }
__device__ inline float asf_hi(uint32_t u){ union { uint32_t u; float f; } a; a.u = u & 0xFFFF0000u; return a.f; }

// ================= prep: gather tables + W_w swizzle + out-init + histogram ==
// blocks: [0,288) h/gather tables (8 nodes each) | [288,291) wswizzle
//         [291,547) out-init | [547,595) histogram
__global__ __launch_bounds__(256) void prep_kernel(
    const float* __restrict__ s_elec, const float* __restrict__ v_elec,
    const float* __restrict__ s_nuc,  const float* __restrict__ v_nuc,
    const float* __restrict__ W_h1, const float* __restrict__ W_h2,
    const float* __restrict__ W_w,
    const int* __restrict__ receivers,
    ushort_t* __restrict__ tabA, ushort_t* __restrict__ tabB,
    short* __restrict__ fragH, short* __restrict__ fragL,
    int* __restrict__ bh, float* __restrict__ out)
{
    int b = blockIdx.x, tid = threadIdx.x;
    __shared__ float sls[8][64];
    __shared__ float hidls[128][8];
    __shared__ int hist[1024];

    if (b < 288){
        int t, node0;
        if (b < 32){ t = 0; node0 = b*8; }
        else if (b < 160){ t = 1; node0 = (b-32)*8; }
        else { t = 2; node0 = (b-160)*8; }
        int tp = t + 1;
        const float* src = (t == 0) ? s_nuc : s_elec;
        const float* vsrc = (t == 0) ? v_nuc : v_elec;
        long baseA = (t == 0) ? 0 : (t == 1 ? 32768 : 163840);
        long baseB = (t == 0) ? 0 : (t == 1 ? 65536 : 327680);
        for (int i = tid; i < 512; i += 256){ int n = i >> 6, f = i & 63; sls[n][f] = src[(node0+n)*64 + f]; }
        __syncthreads();
        {
            int j = tid & 127, nh = tid >> 7;
            const float* w1 = W_h1 + (long)tp*64*128;
            float a0=0,a1=0,a2=0,a3=0;
            #pragma unroll 8
            for (int f = 0; f < 64; f++){
                float w = w1[f*128 + j];
                a0 += sls[nh*4+0][f]*w; a1 += sls[nh*4+1][f]*w;
                a2 += sls[nh*4+2][f]*w; a3 += sls[nh*4+3][f]*w;
            }
            float4_t hv = { silu_f(a0), silu_f(a1), silu_f(a2), silu_f(a3) };
            *(float4_t*)&hidls[j][nh*4] = hv;
        }
        __syncthreads();
        if (tid < 192){
            const float* w2 = W_h2 + (long)tp*128*192;
            float acc[8] = {0,0,0,0,0,0,0,0};
            #pragma unroll 4
            for (int h = 0; h < 128; h++){
                float w = w2[h*192 + tid];
                float4_t ha = *(float4_t*)&hidls[h][0];
                float4_t hb = *(float4_t*)&hidls[h][4];
                acc[0]+=ha[0]*w; acc[1]+=ha[1]*w; acc[2]+=ha[2]*w; acc[3]+=ha[3]*w;
                acc[4]+=hb[0]*w; acc[5]+=hb[1]*w; acc[6]+=hb[2]*w; acc[7]+=hb[3]*w;
            }
            int p = tid >> 6, d2 = tid & 63;
            if (p == 0){
                #pragma unroll
                for (int n = 0; n < 8; n++)
                    tabA[baseA + (long)((node0+n)*64 + d2)*2 + 0] = bfu(acc[n]);
            } else if (p == 2){
                #pragma unroll
                for (int n = 0; n < 8; n++)
                    tabA[baseA + (long)((node0+n)*64 + d2)*2 + 1] = bfu(acc[n]);
            } else {
                #pragma unroll
                for (int n = 0; n < 8; n++){
                    const float* vp = vsrc + (long)(node0+n)*192 + d2*3;
                    long o = baseB + (long)((node0+n)*64 + d2)*4;
                    tabB[o+0] = bfu(acc[n]*vp[0]);
                    tabB[o+1] = bfu(acc[n]*vp[1]);
                    tabB[o+2] = bfu(acc[n]*vp[2]);
                }
            }
        }
    } else if (b < 291){
        int t = b - 288, tp = t + 1;
        const float* W = W_w + (long)tp*64*192;
        for (int idx = tid; idx < 12288; idx += 256){
            int j    = idx & 7;
            int lane = (idx >> 3) & 63;
            int ks   = (idx >> 9) & 1;
            int nt   = idx >> 10;
            int k = ks*32 + ((lane >> 4) & 3)*8 + j;
            int n = nt*16 + (lane & 15);
            float v = W[k*192 + n];
            short hi = f2bf_rne(v);
            short lo = f2bf_rne(v - bf2f(hi));
            fragH[t*12288 + idx] = hi;
            fragL[t*12288 + idx] = lo;
        }
    } else if (b < 547){
        int i = (b - 291)*256 + tid;
        int n = i >> 6, c4 = i & 63;
        float4_t v;
        if (c4 < 16) v = *(const float4_t*)(s_elec + n*64 + c4*4);
        else         v = *(const float4_t*)(v_elec + n*192 + (c4-16)*4);
        *(float4_t*)(out + n*256 + c4*4) = v;
    } else {
        int hb = b - 547, t = hb >> 4, blk = hb & 15;
        for (int i = tid; i < 1024; i += 256) hist[i] = 0;
        __syncthreads();
        long base = (long)(t+1)*E_EDGES + blk*8192;
        #pragma unroll 4
        for (int it = 0; it < 32; it++){
            int r = receivers[base + it*256 + tid];
            atomicAdd(&hist[r], 1);
        }
        __syncthreads();
        for (int bin = tid; bin < 1024; bin += 256)
            bh[(t*1024 + bin)*NBLK + blk] = hist[bin];
    }
}

// ================= scan ======================================================
__global__ __launch_bounds__(1024) void scan_kernel(int* __restrict__ bh,
                                                    int* __restrict__ offs,
                                                    int* __restrict__ counts){
    __shared__ int buf[1024];
    int tid = threadIdx.x;
    int base = tid*48;
    int vals[48];
    const int4_t* p = (const int4_t*)(bh + base);
    int s = 0;
    #pragma unroll
    for (int j = 0; j < 12; j++){
        int4_t x = p[j];
        vals[j*4+0]=x[0]; vals[j*4+1]=x[1]; vals[j*4+2]=x[2]; vals[j*4+3]=x[3];
        s += x[0]+x[1]+x[2]+x[3];
    }
    buf[tid] = s;
    __syncthreads();
    int x = s;
    for (int off = 1; off < 1024; off <<= 1){
        int y = (tid >= off) ? buf[tid - off] : 0;
        __syncthreads();
        x += y; buf[tid] = x;
        __syncthreads();
    }
    int run = x - s;
    #pragma unroll
    for (int k = 0; k < 3; k++){
        int tb = tid*3 + k;
        offs[tb] = run;
        int c = 0;
        #pragma unroll
        for (int j = 0; j < 16; j++){
            int v = vals[k*16 + j];
            bh[base + k*16 + j] = run;
            run += v; c += v;
        }
        counts[tb] = c;
    }
}

// ================= scatter ===================================================
__global__ __launch_bounds__(256) void scatter_kernel(const int* __restrict__ receivers,
                                                      const int* __restrict__ senders,
                                                      const int* __restrict__ bh,
                                                      int* __restrict__ sorted){
    int hb = blockIdx.x, t = hb >> 4, blk = hb & 15;
    int tid = threadIdx.x;
    __shared__ int cur[1024];
    for (int bin = tid; bin < 1024; bin += 256) cur[bin] = bh[(t*1024 + bin)*NBLK + blk];
    __syncthreads();
    long base = (long)(t+1)*E_EDGES + blk*8192;
    #pragma unroll 2
    for (int it = 0; it < 32; it++){
        int e = blk*8192 + it*256 + tid;
        int r = receivers[base + it*256 + tid];
        int snd = senders[base + it*256 + tid];
        int pos = atomicAdd(&cur[r], 1);
        sorted[pos] = e | (snd << 17);
    }
}

// ================= main fused kernel: one block per (type, target) ===========
__global__ __launch_bounds__(256) void main_kernel(
    const float* __restrict__ dist, const float* __restrict__ dirs,
    const float* __restrict__ W_V, const float* __restrict__ W_U,
    const float* __restrict__ W_g1, const float* __restrict__ W_g2,
    const ushort_t* __restrict__ tabA, const ushort_t* __restrict__ tabB,
    const short* __restrict__ fragH, const short* __restrict__ fragL,
    const int* __restrict__ counts, const int* __restrict__ offs, const int* __restrict__ sorted,
    float* __restrict__ out)
{
    int b = blockIdx.x;
    int t = b >> 10, node = b & 1023, tp = t + 1;
    const ushort_t* ta = tabA + ((t == 0) ? 0 : (t == 1 ? 32768 : 163840));
    const ushort_t* tb = tabB + ((t == 0) ? 0 : (t == 1 ? 65536 : 327680));
    const float* dbase = dist + (long)tp*E_EDGES*64;
    const float* dirbase = dirs + (long)tp*E_EDGES*3;

    int tid = threadIdx.x;
    int w = tid >> 6, l = tid & 63;
    int q = l >> 4, c16 = l & 15;
    int d = w*16 + c16;

    __shared__ short AH[2][2][64][8];   // [buf][ks][lane][j]
    __shared__ short AL[2][2][64][8];
    __shared__ float dls[2][16][3];
    __shared__ int eid[MAXCHUNK];
    __shared__ int sid[MAXCHUNK];
    __shared__ float zs[64];
    __shared__ float zv[64][3];
    __shared__ float VvL[192], UvL[192];
    __shared__ float gin[128], hidl[128], aL[192], vdotL[64];

    // B fragments (W_w hi/lo) in registers: wave w -> col tiles {w, w+4, w+8}
    short8 bhf[3][2], blf[3][2];
    #pragma unroll
    for (int ni = 0; ni < 3; ni++){
        int nt = w + ni*4;
        #pragma unroll
        for (int ks = 0; ks < 2; ks++){
            long base = (long)t*12288 + ((nt*2 + ks)*64 + l)*8;
            bhf[ni][ks] = *(const short8*)(fragH + base);
            blf[ni][ks] = *(const short8*)(fragL + base);
        }
    }

    float acc_s = 0.f, acc_v0 = 0.f, acc_v1 = 0.f, acc_v2 = 0.f;

    int deg   = counts[t*1024 + node];
    int start = offs[t*1024 + node];

    int m = tid >> 4, seg = tid & 15;
    int ks_w = seg >> 3, quad_w = (seg >> 1) & 3, j0_w = (seg & 1)*4;
    int lane2 = m | (quad_w << 4);
    int mm = tid / 3, ii = tid - mm*3;   // dirs staging roles (tid<48)

    const float4_t z4 = {0.f,0.f,0.f,0.f};

    for (int cbase = 0; cbase < deg; cbase += MAXCHUNK){
        int chunk = deg - cbase; if (chunk > MAXCHUNK) chunk = MAXCHUNK;
        __syncthreads();   // protect eid/sid from previous chunk's readers
        {
            int v = 0;
            if (tid < chunk) v = sorted[(long)start + cbase + tid];
            eid[tid] = v & 131071;
            sid[tid] = ((unsigned)v) >> 17;
        }
        __syncthreads();

        int ngroups = (chunk + 15) >> 4;
        // prologue: group 0 A + dirs + gathers
        float4_t dv = z4;
        if (m < chunk) dv = *(const float4_t*)(dbase + (long)eid[m]*64 + seg*4);
        float dirv = 0.f;
        if (tid < 48 && mm < chunk) dirv = dirbase[(long)eid[mm]*3 + ii];
        uint32_t gA[4]; uint2_t gB[4];
        #pragma unroll
        for (int r = 0; r < 4; r++){
            int s = sid[q*4 + r];
            gA[r] = *(const uint32_t*)(ta + (long)(s*64 + d)*2);
            gB[r] = *(const uint2_t*)(tb + (long)(s*64 + d)*4);
        }

        for (int g = 0; g < ngroups; g++){
            int buf = g & 1;
            // write staged A (RNE hi/lo split) + dirs
            {
                short4_t h4, l4;
                #pragma unroll
                for (int jj = 0; jj < 4; jj++){
                    short hi = f2bf_rne(dv[jj]);
                    h4[jj] = hi;
                    l4[jj] = f2bf_rne(dv[jj] - bf2f(hi));
                }
                *(short4_t*)&AH[buf][ks_w][lane2][j0_w] = h4;
                *(short4_t*)&AL[buf][ks_w][lane2][j0_w] = l4;
                if (tid < 48) dls[buf][mm][ii] = dirv;
            }
            // prefetch group g+1 (A rows, dirs, gathers) — in flight across barrier+compute
            float4_t dvn = z4; float dirn = 0.f;
            uint32_t gAn[4] = {0,0,0,0}; uint2_t gBn[4] = {{0,0},{0,0},{0,0},{0,0}};
            if (g + 1 < ngroups){
                int li = (g+1)*16 + m;
                if (li < chunk) dvn = *(const float4_t*)(dbase + (long)eid[li]*64 + seg*4);
                int li2 = (g+1)*16 + mm;
                if (tid < 48 && li2 < chunk) dirn = dirbase[(long)eid[li2]*3 + ii];
                #pragma unroll
                for (int r = 0; r < 4; r++){
                    int s = sid[(g+1)*16 + q*4 + r];
                    gAn[r] = *(const uint32_t*)(ta + (long)(s*64 + d)*2);
                    gBn[r] = *(const uint2_t*)(tb + (long)(s*64 + d)*4);
                }
            }
            __syncthreads();

            // MFMA: we = dist @ W_w, split-bf16 3-term
            short8 ah0 = *(short8*)&AH[buf][0][l][0];
            short8 ah1 = *(short8*)&AH[buf][1][l][0];
            short8 al0 = *(short8*)&AL[buf][0][l][0];
            short8 al1 = *(short8*)&AL[buf][1][l][0];
            float4_t C[3];
            #pragma unroll
            for (int ni = 0; ni < 3; ni++){
                float4_t acc = z4;
                acc = __builtin_amdgcn_mfma_f32_16x16x32_bf16(ah0, bhf[ni][0], acc, 0, 0, 0);
                acc = __builtin_amdgcn_mfma_f32_16x16x32_bf16(ah1, bhf[ni][1], acc, 0, 0, 0);
                acc = __builtin_amdgcn_mfma_f32_16x16x32_bf16(ah0, blf[ni][0], acc, 0, 0, 0);
                acc = __builtin_amdgcn_mfma_f32_16x16x32_bf16(ah1, blf[ni][1], acc, 0, 0, 0);
                acc = __builtin_amdgcn_mfma_f32_16x16x32_bf16(al0, bhf[ni][0], acc, 0, 0, 0);
                acc = __builtin_amdgcn_mfma_f32_16x16x32_bf16(al1, bhf[ni][1], acc, 0, 0, 0);
                C[ni] = acc;
            }

            // epilogue: phi = we*hx folded via bf16 gather tables
            #pragma unroll
            for (int r = 0; r < 4; r++){
                int mr = q*4 + r;
                float hs  = asf_lo(gA[r]);
                float hvs = asf_hi(gA[r]);
                float hv0 = asf_lo(gB[r][0]);
                float hv1 = asf_hi(gB[r][0]);
                float hv2 = asf_lo(gB[r][1]);
                acc_s += C[0][r] * hs;
                float pvs = C[2][r] * hvs;
                acc_v0 += C[1][r]*hv0 + pvs * dls[buf][mr][0];
                acc_v1 += C[1][r]*hv1 + pvs * dls[buf][mr][1];
                acc_v2 += C[1][r]*hv2 + pvs * dls[buf][mr][2];
            }
            dv = dvn; dirv = dirn;
            #pragma unroll
            for (int r = 0; r < 4; r++){ gA[r] = gAn[r]; gB[r] = gBn[r]; }
        }
    }

    // cross-quad reduction (C rows live in different quads)
    acc_s  += __shfl_xor(acc_s, 16);  acc_s  += __shfl_xor(acc_s, 32);
    acc_v0 += __shfl_xor(acc_v0, 16); acc_v0 += __shfl_xor(acc_v0, 32);
    acc_v1 += __shfl_xor(acc_v1, 16); acc_v1 += __shfl_xor(acc_v1, 32);
    acc_v2 += __shfl_xor(acc_v2, 16); acc_v2 += __shfl_xor(acc_v2, 32);
    __syncthreads();
    if (l < 16){
        zs[d] = acc_s;
        zv[d][0] = acc_v0; zv[d][1] = acc_v1; zv[d][2] = acc_v2;
    }
    __syncthreads();

    // node update
    if (tid < 192){
        int i = tid >> 6, f = tid & 63;
        const float* wv = W_V + (long)tp*64*64;
        const float* wu = W_U + (long)tp*64*64;
        float av = 0.f, au = 0.f;
        #pragma unroll 8
        for (int dd = 0; dd < 64; dd++){
            float z = zv[dd][i];
            av += z * wv[dd*64 + f];
            au += z * wu[dd*64 + f];
        }
        VvL[f*3 + i] = av;
        UvL[f*3 + i] = au;
    }
    __syncthreads();
    if (tid < 64){
        int f = tid;
        float v0 = VvL[f*3], v1 = VvL[f*3+1], v2 = VvL[f*3+2];
        float u0 = UvL[f*3], u1 = UvL[f*3+1], u2 = UvL[f*3+2];
        gin[f] = zs[f];
        gin[64 + f] = v0*v0 + v1*v1 + v2*v2;
        vdotL[f] = u0*v0 + u1*v1 + u2*v2;
    }
    __syncthreads();
    if (tid < 128){
        const float* w1 = W_g1 + (long)tp*128*128;
        float acc = 0.f;
        #pragma unroll 8
        for (int c = 0; c < 128; c++) acc += gin[c] * w1[c*128 + tid];
        hidl[tid] = silu_f(acc);
    }
    __syncthreads();
    if (tid < 192){
        const float* w2 = W_g2 + (long)tp*128*192;
        float acc = 0.f;
        #pragma unroll 8
        for (int h = 0; h < 128; h++) acc += hidl[h] * w2[h*192 + tid];
        aL[tid] = acc;
    }
    __syncthreads();
    if (tid < 64){
        int f = tid;
        float upd = aL[128 + f] * vdotL[f] + aL[f];
        atomicAdd(&out[node*256 + f], upd);
    }
    if (tid < 192){
        int i = tid >> 6, f = tid & 63;
        float updv = UvL[f*3 + i] * aL[64 + f];
        atomicAdd(&out[node*256 + 64 + f*3 + i], updv);
    }
}

// ================= launcher ==================================================
extern "C" void kernel_launch(void* const* d_in, const int* in_sizes, int n_in,
                              void* d_out, int out_size, void* d_ws, size_t ws_size,
                              hipStream_t stream){
    const float* s_elec  = (const float*)d_in[0];
    const float* v_elec  = (const float*)d_in[1];
    const float* s_nuc   = (const float*)d_in[2];
    const float* v_nuc   = (const float*)d_in[3];
    const float* dist    = (const float*)d_in[4];
    const float* dirs    = (const float*)d_in[5];
    const float* W_w     = (const float*)d_in[6];
    const float* W_h1    = (const float*)d_in[7];
    const float* W_h2    = (const float*)d_in[8];
    const float* W_g1    = (const float*)d_in[9];
    const float* W_g2    = (const float*)d_in[10];
    const float* W_V     = (const float*)d_in[11];
    const float* W_U     = (const float*)d_in[12];
    const int* senders   = (const int*)d_in[13];
    const int* receivers = (const int*)d_in[14];
    float* out = (float*)d_out;
    char* ws = (char*)d_ws;

    // workspace layout (bytes) — total 3710976 (same proven budget as R2)
    ushort_t* tabA  = (ushort_t*)(ws + 0);        // 589824 B  (h_s, h_vs) bf16
    ushort_t* tabB  = (ushort_t*)(ws + 589824);   // 1179648 B (hv0,hv1,hv2,pad) bf16
    short* fragH  = (short*)(ws + 1769472);       // 73728 B
    short* fragL  = (short*)(ws + 1843200);       // 73728 B
    int*   bh     = (int*)  (ws + 1916928);       // 196608 B
    int*   offs   = (int*)  (ws + 2113536);       // 12288 B
    int*   counts = (int*)  (ws + 2125824);       // 12288 B
    int*   sorted = (int*)  (ws + 2138112);       // 1572864 B -> end 3710976
    if (ws_size < 3710976) return;

    prep_kernel<<<dim3(595), dim3(256), 0, stream>>>(
        s_elec, v_elec, s_nuc, v_nuc, W_h1, W_h2, W_w, receivers,
        tabA, tabB, fragH, fragL, bh, out);
    scan_kernel<<<dim3(1), dim3(1024), 0, stream>>>(bh, offs, counts);
    scatter_kernel<<<dim3(48), dim3(256), 0, stream>>>(receivers, senders, bh, sorted);
    main_kernel<<<dim3(3072), dim3(256), 0, stream>>>(
        dist, dirs, W_V, W_U, W_g1, W_g2,
        tabA, tabB, fragH, fragL, counts, offs, sorted, out);
}